// Round 5
// baseline (78.104 us; speedup 1.0000x reference)
//
#include <hip/hip_runtime.h>

// EuclidConv + BatchNorm (training stats), fp32 in/out.
// y = 2*conv(x,w) + t1 (+t2 cancels in BN).  bf16 MFMA implicit GEMM:
//   M=25088 pixels, N=256 chans, K=9 taps*128 ci.
// Round 5: round-4 verified base + SINGLE delta: 2-phase double-buffered
// pipeline (T3 minimum form: STAGE(next) issued before COMPUTE(cur), one
// __syncthreads per K-step). Everything else byte-identical to round 4.

typedef short  bf16x8 __attribute__((ext_vector_type(8)));
typedef float  f32x4  __attribute__((ext_vector_type(4)));

#define NPIX   784
#define CI_    128
#define CO_    256
#define NB_    32
#define M_     25088
#define SHIFT_ 1152.0f
#define BN_EPS 1e-5f
#define M_TOT  25088

// ws layout (bytes): xp [32][30][30][128] bf16 = 7,372,800 ; s [32][30][30] f32 ;
// stats [2][256] f32 ; wp [36][16][4][16][8] bf16 = 589,824 (round-2 layout)
#define S_OFF   7372800
#define ST_OFF  7488000
#define WP_OFF  7490048
#define ZERO_F4 468128            // (ST_OFF + 2048) / 16 : zeroes xp + s + stats

__device__ __forceinline__ unsigned short f2bf(float f) {
    unsigned int u = __float_as_uint(f);
    unsigned int r = (u + 0x7FFFu + ((u >> 16) & 1u)) >> 16;
    return (unsigned short)r;
}

__device__ __forceinline__ void gload_lds16(const void* gsrc, void* ldst) {
    __builtin_amdgcn_global_load_lds(
        (const __attribute__((address_space(1))) void*)gsrc,
        (__attribute__((address_space(3))) void*)ldst, 16, 0, 0);
}

__global__ __launch_bounds__(256) void init_ws(float* ws) {
    int i = blockIdx.x * 256 + threadIdx.x;
    if (i < ZERO_F4) ((f32x4*)ws)[i] = (f32x4){0.f, 0.f, 0.f, 0.f};
}

// ---- pack x: NCHW f32 -> padded NHWC bf16, plus s = sum_ci x^2 (round-2) ----
__global__ __launch_bounds__(256) void pack_x(const float* __restrict__ x,
                                              unsigned short* __restrict__ xp,
                                              float* __restrict__ s) {
    const int n = blockIdx.x / 28, h = blockIdx.x % 28, tid = threadIdx.x;
    __shared__ float xs[128][29];
    __shared__ float part[8][28];

    #pragma unroll
    for (int i = 0; i < 14; ++i) {
        int e = tid + i * 256;
        int ci = e / 28, w = e - ci * 28;
        xs[ci][w] = x[(size_t)(n * 128 + ci) * 784 + h * 28 + w];
    }
    __syncthreads();
    #pragma unroll
    for (int i = 0; i < 14; ++i) {
        int e = tid + i * 256;
        int w = e >> 7, ci = e & 127;
        xp[((size_t)(n * 30 + h + 1) * 30 + (w + 1)) * 128 + ci] = f2bf(xs[ci][w]);
    }
    if (tid < 224) {
        int grp = tid / 28, w = tid - grp * 28;
        float a = 0.f;
        #pragma unroll
        for (int ci = grp * 16; ci < grp * 16 + 16; ++ci) a = fmaf(xs[ci][w], xs[ci][w], a);
        part[grp][w] = a;
    }
    __syncthreads();
    if (tid < 28) {
        float a = 0.f;
        #pragma unroll
        for (int g = 0; g < 8; ++g) a += part[g][tid];
        s[n * 900 + (h + 1) * 30 + (tid + 1)] = a;
    }
}

// ---- pack w (round-2 verified): wp[kblk(36)][ng(16)][kb(4)][cc(16)][k8(8)] ----
__global__ __launch_bounds__(256) void pack_w(const float* __restrict__ w,
                                              unsigned short* __restrict__ wp) {
    int o = blockIdx.x * 256 + threadIdx.x;      // < 294912
    int k8   = o & 7;
    int cc   = (o >> 3) & 15;
    int kb   = (o >> 7) & 3;
    int ng   = (o >> 9) & 15;
    int kblk = o >> 13;                          // 0..35
    int tap  = kblk >> 2;
    int ci   = (kblk & 3) * 32 + kb * 8 + k8;
    int co   = ng * 16 + cc;
    wp[o] = f2bf(w[(size_t)(co * 128 + ci) * 9 + tap]);
}

// ---- MFMA implicit GEMM: BM=128, BN=64, 4 waves (2x2 of 64x32), 2-phase dbuf ----
__global__ __launch_bounds__(256, 3) void econv(
        const unsigned short* __restrict__ xp, const unsigned short* __restrict__ wp,
        const float* __restrict__ s, float* __restrict__ y, float* __restrict__ stats) {
    __shared__ unsigned short As[2][8192];   // 2 x 16KB  [row(128)][slot(8)][8]
    __shared__ unsigned short Bs[2][4096];   // 2 x 8KB   [q(2)][ngl(4)][kb(4)][cc(16)][8]
    __shared__ float t1s[128];

    const int tid = threadIdx.x;
    // XCD-aware bijective swizzle (784 = 8*98)
    int bid = blockIdx.x;
    int swz = (bid & 7) * 98 + (bid >> 3);
    const int nb = swz & 3;
    const int mb = swz >> 2;
    const int gblock = mb * 128;
    const int nblock = nb * 64;
    const int ng0 = nb * 4;

    // t1 = 3x3 box of padded per-pixel sum of x^2
    if (tid < 128) {
        int g = gblock + tid; int n = g / 784, p = g - n * 784;
        int h = p / 28, wq = p - h * 28;
        const float* sb = s + n * 900 + h * 30 + wq;
        t1s[tid] = (sb[0] + sb[1] + sb[2]) + (sb[30] + sb[31] + sb[32]) + (sb[60] + sb[61] + sb[62]);
    }

    int rowoff[4];
    {
        int r0 = tid >> 3;
        #pragma unroll
        for (int i = 0; i < 4; ++i) {
            int g = gblock + r0 + i * 32;
            int n = g / 784, p = g - n * 784;
            int h = p / 28, wc = p - h * 28;
            rowoff[i] = (n * 30 + h) * 30 + wc;
        }
    }
    const int sig8 = (((tid & 7) ^ ((tid >> 3) & 7)) << 3);
    const int lane = tid & 63;
    const int wid  = tid >> 6;
    const int wm = wid >> 1, wn = wid & 1;
    const int l15 = lane & 15, l16 = lane >> 4;

    f32x4 acc[4][2];
    #pragma unroll
    for (int a_ = 0; a_ < 4; ++a_)
        #pragma unroll
        for (int b_ = 0; b_ < 2; ++b_) acc[a_][b_] = (f32x4){0.f, 0.f, 0.f, 0.f};

#define STAGE(b, ks) {                                                          \
    const int tap_ = (ks) >> 1, half_ = (ks) & 1;                               \
    const int tapoff_ = (tap_ / 3) * 30 + (tap_ - (tap_ / 3) * 3);              \
    const unsigned short* xa = xp + half_ * 64 + sig8;                          \
    _Pragma("unroll") for (int i_ = 0; i_ < 4; ++i_)                            \
        gload_lds16(xa + (size_t)(rowoff[i_] + tapoff_) * 128,                  \
                    &As[b][(tid + i_ * 256) * 8]);                              \
    const int kb0_ = tap_ * 4 + half_ * 2;                                      \
    _Pragma("unroll") for (int i_ = 0; i_ < 2; ++i_) {                          \
        int c_ = tid + i_ * 256;                                                \
        int q_ = c_ >> 8, ngl_ = (c_ >> 6) & 3, rest_ = c_ & 63;                \
        int srcc_ = ((kb0_ + q_) * 16 + ng0 + ngl_) * 64 + rest_;               \
        gload_lds16(wp + (size_t)srcc_ * 8, &Bs[b][c_ * 8]);                    \
    }                                                                           \
}

#define COMPUTE(b) {                                                            \
    _Pragma("unroll") for (int q_ = 0; q_ < 2; ++q_) {                          \
        bf16x8 aF[4], bF[2];                                                    \
        _Pragma("unroll") for (int fm_ = 0; fm_ < 4; ++fm_) {                   \
            int r_ = wm * 64 + fm_ * 16 + l15;                                  \
            int j_ = (q_ * 4 + l16) ^ (r_ & 7);                                 \
            aF[fm_] = *(const bf16x8*)&As[b][(r_ * 8 + j_) * 8];                \
        }                                                                       \
        _Pragma("unroll") for (int fn_ = 0; fn_ < 2; ++fn_) {                   \
            int c_ = q_ * 256 + (wn * 2 + fn_) * 64 + l16 * 16 + l15;           \
            bF[fn_] = *(const bf16x8*)&Bs[b][c_ * 8];                           \
        }                                                                       \
        _Pragma("unroll") for (int fm_ = 0; fm_ < 4; ++fm_)                     \
            _Pragma("unroll") for (int fn_ = 0; fn_ < 2; ++fn_)                 \
                acc[fm_][fn_] = __builtin_amdgcn_mfma_f32_16x16x32_bf16(        \
                    aF[fm_], bF[fn_], acc[fm_][fn_], 0, 0, 0);                  \
    }                                                                           \
}

    STAGE(0, 0);
    __syncthreads();
    #pragma unroll 1
    for (int ks = 0; ks < 18; ks += 2) {
        STAGE(1, ks + 1);          // issue next-tile loads (hide under compute)
        COMPUTE(0);
        __syncthreads();           // vmcnt(0)+barrier: buffer 1 ready
        if (ks + 2 < 18) STAGE(0, ks + 2);
        COMPUTE(1);
        __syncthreads();
    }
#undef STAGE
#undef COMPUTE

    // epilogue (round-4 verified): y = 2*acc + t1; shifted stats -> atomics
    float sSum[2] = {0.f, 0.f}, sSq[2] = {0.f, 0.f};
    #pragma unroll
    for (int fm = 0; fm < 4; ++fm) {
        #pragma unroll
        for (int j = 0; j < 4; ++j) {
            int r = wm * 64 + fm * 16 + l16 * 4 + j;
            int g = gblock + r;
            int n = g / 784, p = g - n * 784;
            float t1v = t1s[r];
            float* yb = y + (size_t)n * 200704 + p;
            #pragma unroll
            for (int fn = 0; fn < 2; ++fn) {
                int co = nblock + wn * 32 + fn * 16 + l15;
                float v = fmaf(2.f, acc[fm][fn][j], t1v);
                yb[co * 784] = v;
                float d = v - SHIFT_;
                sSum[fn] += d;
                sSq[fn] = fmaf(d, d, sSq[fn]);
            }
        }
    }
    #pragma unroll
    for (int fn = 0; fn < 2; ++fn) {
        float a = sSum[fn], b2 = sSq[fn];
        a  += __shfl_xor(a, 16);  a  += __shfl_xor(a, 32);
        b2 += __shfl_xor(b2, 16); b2 += __shfl_xor(b2, 32);
        if (l16 == 0) {
            int co = nblock + wn * 32 + fn * 16 + l15;
            atomicAdd(&stats[co], a);
            atomicAdd(&stats[256 + co], b2);
        }
    }
}

__global__ __launch_bounds__(256) void bn_apply(
        float* __restrict__ y, const float* __restrict__ stats,
        const float* __restrict__ gamma, const float* __restrict__ beta) {
    const int TOTAL4 = NB_ * CO_ * NPIX / 4;
    int i4 = blockIdx.x * 256 + threadIdx.x;
    if (i4 >= TOTAL4) return;
    int c = (i4 / (NPIX / 4)) & (CO_ - 1);
    float su = stats[c];
    float s2 = stats[CO_ + c];
    const float invM = 1.0f / (float)M_TOT;
    float ms   = su * invM;
    float var  = fmaf(-ms, ms, s2 * invM);
    float mean = SHIFT_ + ms;
    float scale = rsqrtf(var + BN_EPS) * gamma[c];
    float bias  = beta[c] - mean * scale;
    f32x4 v = ((const f32x4*)y)[i4];
    v.x = fmaf(v.x, scale, bias);
    v.y = fmaf(v.y, scale, bias);
    v.z = fmaf(v.z, scale, bias);
    v.w = fmaf(v.w, scale, bias);
    ((f32x4*)y)[i4] = v;
}

extern "C" void kernel_launch(void* const* d_in, const int* in_sizes, int n_in,
                              void* d_out, int out_size, void* d_ws, size_t ws_size,
                              hipStream_t stream) {
    const float* x     = (const float*)d_in[0];
    const float* w     = (const float*)d_in[1];
    const float* gamma = (const float*)d_in[2];
    const float* beta  = (const float*)d_in[3];
    float* y = (float*)d_out;

    char* ws = (char*)d_ws;
    unsigned short* xp    = (unsigned short*)(ws);
    float*          s     = (float*)(ws + S_OFF);
    float*          stats = (float*)(ws + ST_OFF);
    unsigned short* wp    = (unsigned short*)(ws + WP_OFF);

    init_ws<<<(ZERO_F4 + 255) / 256, 256, 0, stream>>>((float*)ws);
    pack_x<<<NB_ * 28, 256, 0, stream>>>(x, xp, s);
    pack_w<<<1152, 256, 0, stream>>>(w, wp);
    econv<<<784, 256, 0, stream>>>(xp, wp, s, y, stats);
    bn_apply<<<(NB_ * CO_ * NPIX / 4 + 255) / 256, 256, 0, stream>>>(y, stats, gamma, beta);
}

// Round 7
// 66.045 us; speedup vs baseline: 1.1826x; 1.1826x over previous
//
#include <hip/hip_runtime.h>

// EuclidConv + BatchNorm (training stats), fp32 in/out.
// y = 2*conv(x,w) + t1 (+t2 cancels in BN).  bf16 MFMA implicit GEMM:
//   M=25088 pixels, N=256 chans, K=9 taps*128 ci.
// Round 7: round-6 structure, ONE fix: slab = 10 padded rows (4864 chunks),
// because image-crossing blocks span up to 10 padded rows (row index jumps
// by 3 at image boundary). Round 6's 8-row slab overflowed -> NaN.

typedef short  bf16x8 __attribute__((ext_vector_type(8)));
typedef float  f32x4  __attribute__((ext_vector_type(4)));

#define NPIX   784
#define CI_    128
#define CO_    256
#define NB_    32
#define M_     25088
#define SHIFT_ 1152.0f
#define BN_EPS 1e-5f
#define M_TOT  25088

// ws layout (bytes): xp [32][30][30][128] bf16 = 7,372,800 ; s [32][30][30] f32 ;
// stats [2][256] f32 ; wp [36][16][4][16][8] bf16 = 589,824 (round-2 layout)
#define S_OFF   7372800
#define ST_OFF  7488000
#define WP_OFF  7490048
#define ZERO_F4 468128            // (ST_OFF + 2048) / 16 : zeroes xp + s + stats

#define SLAB_CHUNKS 4864          // 19*256; >= 10 rows * 30 * 16 = 4800

__device__ __forceinline__ unsigned short f2bf(float f) {
    unsigned int u = __float_as_uint(f);
    unsigned int r = (u + 0x7FFFu + ((u >> 16) & 1u)) >> 16;
    return (unsigned short)r;
}

__device__ __forceinline__ void gload_lds16(const void* gsrc, void* ldst) {
    __builtin_amdgcn_global_load_lds(
        (const __attribute__((address_space(1))) void*)gsrc,
        (__attribute__((address_space(3))) void*)ldst, 16, 0, 0);
}

__global__ __launch_bounds__(256) void init_ws(float* ws) {
    int i = blockIdx.x * 256 + threadIdx.x;
    if (i < ZERO_F4) ((f32x4*)ws)[i] = (f32x4){0.f, 0.f, 0.f, 0.f};
}

// ---- pack x: NCHW f32 -> padded NHWC bf16, plus s = sum_ci x^2 (round-2) ----
__global__ __launch_bounds__(256) void pack_x(const float* __restrict__ x,
                                              unsigned short* __restrict__ xp,
                                              float* __restrict__ s) {
    const int n = blockIdx.x / 28, h = blockIdx.x % 28, tid = threadIdx.x;
    __shared__ float xs[128][29];
    __shared__ float part[8][28];

    #pragma unroll
    for (int i = 0; i < 14; ++i) {
        int e = tid + i * 256;
        int ci = e / 28, w = e - ci * 28;
        xs[ci][w] = x[(size_t)(n * 128 + ci) * 784 + h * 28 + w];
    }
    __syncthreads();
    #pragma unroll
    for (int i = 0; i < 14; ++i) {
        int e = tid + i * 256;
        int w = e >> 7, ci = e & 127;
        xp[((size_t)(n * 30 + h + 1) * 30 + (w + 1)) * 128 + ci] = f2bf(xs[ci][w]);
    }
    if (tid < 224) {
        int grp = tid / 28, w = tid - grp * 28;
        float a = 0.f;
        #pragma unroll
        for (int ci = grp * 16; ci < grp * 16 + 16; ++ci) a = fmaf(xs[ci][w], xs[ci][w], a);
        part[grp][w] = a;
    }
    __syncthreads();
    if (tid < 28) {
        float a = 0.f;
        #pragma unroll
        for (int g = 0; g < 8; ++g) a += part[g][tid];
        s[n * 900 + (h + 1) * 30 + (tid + 1)] = a;
    }
}

// ---- pack w (round-2 verified): wp[kblk(36)][ng(16)][kb(4)][cc(16)][k8(8)] ----
__global__ __launch_bounds__(256) void pack_w(const float* __restrict__ w,
                                              unsigned short* __restrict__ wp) {
    int o = blockIdx.x * 256 + threadIdx.x;      // < 294912
    int k8   = o & 7;
    int cc   = (o >> 3) & 15;
    int kb   = (o >> 7) & 3;
    int ng   = (o >> 9) & 15;
    int kblk = o >> 13;                          // 0..35
    int tap  = kblk >> 2;
    int ci   = (kblk & 3) * 32 + kb * 8 + k8;
    int co   = ng * 16 + cc;
    wp[o] = f2bf(w[(size_t)(co * 128 + ci) * 9 + tap]);
}

// ---- MFMA implicit GEMM: BM=128, BN=64, 4 waves (2x2 of 64x32) ----
// A-slab resident in LDS (staged once, 10 rows); barrier-free K-loop.
__global__ __launch_bounds__(256, 2) void econv(
        const unsigned short* __restrict__ xp, const unsigned short* __restrict__ wp,
        const float* __restrict__ s, float* __restrict__ y, float* __restrict__ stats) {
    __shared__ unsigned short slab[SLAB_CHUNKS * 8];   // 77,824 B: 10 padded rows
    __shared__ float t1s[128];

    const int tid = threadIdx.x;
    // XCD-aware bijective swizzle (784 = 8*98)
    int bid = blockIdx.x;
    int swz = (bid & 7) * 98 + (bid >> 3);
    const int nb = swz & 3;
    const int mb = swz >> 2;
    const int gblock = mb * 128;
    const int nblock = nb * 64;
    const int ng0 = nb * 4;

    // slab covers global padded rows GR0..GR0+9 (crossing blocks need 10)
    const int n0  = gblock / 784;
    const int p0  = gblock - n0 * 784;
    const int GR0 = n0 * 30 + p0 / 28;
    const unsigned short* slabg = xp + (size_t)GR0 * 30 * 128;

    // stage slab once: linear LDS dest, source pre-swizzled.
    // slot sl of pixel Q holds source chunk c = (sl&8)|((sl&7)^(Q&7)).
    #pragma unroll
    for (int i = 0; i < 19; ++i) {
        int sc = tid + i * 256;
        int Q = sc >> 4, sl = sc & 15;
        int c = (sl & 8) | ((sl & 7) ^ (Q & 7));
        gload_lds16(slabg + (size_t)(Q * 16 + c) * 8, &slab[sc * 8]);
    }

    // t1 = 3x3 box of padded per-pixel sum of x^2
    if (tid < 128) {
        int g = gblock + tid; int n = g / 784, p = g - n * 784;
        int h = p / 28, wq = p - h * 28;
        const float* sb = s + n * 900 + h * 30 + wq;
        t1s[tid] = (sb[0] + sb[1] + sb[2]) + (sb[30] + sb[31] + sb[32]) + (sb[60] + sb[61] + sb[62]);
    }

    const int lane = tid & 63;
    const int wid  = tid >> 6;
    const int wm = wid >> 1, wn = wid & 1;
    const int l15 = lane & 15, l16 = lane >> 4;

    // per-lane slab pixel index (3x3 window top-left) for each fm row
    int Pp[4];
    #pragma unroll
    for (int fm = 0; fm < 4; ++fm) {
        int g = gblock + wm * 64 + fm * 16 + l15;
        int n = g / 784, p = g - n * 784;
        int h = p / 28, c = p - h * 28;
        Pp[fm] = (n * 30 + h - GR0) * 30 + c;
    }
    // per-lane B base: each wave's frag read is 1KB contiguous
    const unsigned short* wpl = wp + (size_t)((ng0 + wn * 2) * 64 + l16 * 16 + l15) * 8;

    f32x4 acc[4][2];
    #pragma unroll
    for (int a_ = 0; a_ < 4; ++a_)
        #pragma unroll
        for (int b_ = 0; b_ < 2; ++b_) acc[a_][b_] = (f32x4){0.f, 0.f, 0.f, 0.f};

    __syncthreads();   // slab + t1s ready; no barriers after this point

    #pragma unroll
    for (int tap = 0; tap < 9; ++tap) {
        const int toff = (tap / 3) * 30 + (tap % 3);
        #pragma unroll
        for (int half = 0; half < 2; ++half) {
            bf16x8 aF[2][4], bF[2][2];
            #pragma unroll
            for (int q = 0; q < 2; ++q) {
                #pragma unroll
                for (int fm = 0; fm < 4; ++fm) {
                    int P2 = Pp[fm] + toff;
                    int sl = half * 8 + ((q * 4 + l16) ^ (P2 & 7));
                    aF[q][fm] = *(const bf16x8*)&slab[(P2 * 16 + sl) * 8];
                }
                const int K16 = (tap * 4 + half * 2 + q) * 16;
                #pragma unroll
                for (int fn = 0; fn < 2; ++fn)
                    bF[q][fn] = *(const bf16x8*)&wpl[(size_t)(K16 + fn) * 512];
            }
            #pragma unroll
            for (int q = 0; q < 2; ++q)
                #pragma unroll
                for (int fm = 0; fm < 4; ++fm)
                    #pragma unroll
                    for (int fn = 0; fn < 2; ++fn)
                        acc[fm][fn] = __builtin_amdgcn_mfma_f32_16x16x32_bf16(
                            aF[q][fm], bF[q][fn], acc[fm][fn], 0, 0, 0);
        }
    }

    // epilogue (round-4 verified): y = 2*acc + t1; shifted stats -> atomics
    float sSum[2] = {0.f, 0.f}, sSq[2] = {0.f, 0.f};
    #pragma unroll
    for (int fm = 0; fm < 4; ++fm) {
        #pragma unroll
        for (int j = 0; j < 4; ++j) {
            int r = wm * 64 + fm * 16 + l16 * 4 + j;
            int g = gblock + r;
            int n = g / 784, p = g - n * 784;
            float t1v = t1s[r];
            float* yb = y + (size_t)n * 200704 + p;
            #pragma unroll
            for (int fn = 0; fn < 2; ++fn) {
                int co = nblock + wn * 32 + fn * 16 + l15;
                float v = fmaf(2.f, acc[fm][fn][j], t1v);
                yb[co * 784] = v;
                float d = v - SHIFT_;
                sSum[fn] += d;
                sSq[fn] = fmaf(d, d, sSq[fn]);
            }
        }
    }
    #pragma unroll
    for (int fn = 0; fn < 2; ++fn) {
        float a = sSum[fn], b2 = sSq[fn];
        a  += __shfl_xor(a, 16);  a  += __shfl_xor(a, 32);
        b2 += __shfl_xor(b2, 16); b2 += __shfl_xor(b2, 32);
        if (l16 == 0) {
            int co = nblock + wn * 32 + fn * 16 + l15;
            atomicAdd(&stats[co], a);
            atomicAdd(&stats[256 + co], b2);
        }
    }
}

__global__ __launch_bounds__(256) void bn_apply(
        float* __restrict__ y, const float* __restrict__ stats,
        const float* __restrict__ gamma, const float* __restrict__ beta) {
    const int TOTAL4 = NB_ * CO_ * NPIX / 4;
    int i4 = blockIdx.x * 256 + threadIdx.x;
    if (i4 >= TOTAL4) return;
    int c = (i4 / (NPIX / 4)) & (CO_ - 1);
    float su = stats[c];
    float s2 = stats[CO_ + c];
    const float invM = 1.0f / (float)M_TOT;
    float ms   = su * invM;
    float var  = fmaf(-ms, ms, s2 * invM);
    float mean = SHIFT_ + ms;
    float scale = rsqrtf(var + BN_EPS) * gamma[c];
    float bias  = beta[c] - mean * scale;
    f32x4 v = ((const f32x4*)y)[i4];
    v.x = fmaf(v.x, scale, bias);
    v.y = fmaf(v.y, scale, bias);
    v.z = fmaf(v.z, scale, bias);
    v.w = fmaf(v.w, scale, bias);
    ((f32x4*)y)[i4] = v;
}

extern "C" void kernel_launch(void* const* d_in, const int* in_sizes, int n_in,
                              void* d_out, int out_size, void* d_ws, size_t ws_size,
                              hipStream_t stream) {
    const float* x     = (const float*)d_in[0];
    const float* w     = (const float*)d_in[1];
    const float* gamma = (const float*)d_in[2];
    const float* beta  = (const float*)d_in[3];
    float* y = (float*)d_out;

    char* ws = (char*)d_ws;
    unsigned short* xp    = (unsigned short*)(ws);
    float*          s     = (float*)(ws + S_OFF);
    float*          stats = (float*)(ws + ST_OFF);
    unsigned short* wp    = (unsigned short*)(ws + WP_OFF);

    init_ws<<<(ZERO_F4 + 255) / 256, 256, 0, stream>>>((float*)ws);
    pack_x<<<NB_ * 28, 256, 0, stream>>>(x, xp, s);
    pack_w<<<1152, 256, 0, stream>>>(w, wp);
    econv<<<784, 256, 0, stream>>>(xp, wp, s, y, stats);
    bn_apply<<<(NB_ * CO_ * NPIX / 4 + 255) / 256, 256, 0, stream>>>(y, stats, gamma, beta);
}

// Round 8
// 56.944 us; speedup vs baseline: 1.3716x; 1.1598x over previous
//
#include <hip/hip_runtime.h>

// EuclidConv + BatchNorm (training stats), fp32 in/out.
// y = 2*conv(x,w) + t1 (+t2 cancels in BN).  bf16 MFMA implicit GEMM:
//   M=25088 pixels, N=256 chans, K=9 taps*128 ci.
// Round 8: round-7 verified base + ONE delta: coalesced epilogue.
// Old: 32 scattered 4B stores/thread (64 L2 transactions per store inst).
// New: acc -> LDS transpose (slab reuse, stride-132) -> 8x f32x4 coalesced.

typedef short  bf16x8 __attribute__((ext_vector_type(8)));
typedef float  f32x4  __attribute__((ext_vector_type(4)));

#define NPIX   784
#define CI_    128
#define CO_    256
#define NB_    32
#define M_     25088
#define SHIFT_ 1152.0f
#define BN_EPS 1e-5f
#define M_TOT  25088

// ws layout (bytes): xp [32][30][30][128] bf16 = 7,372,800 ; s [32][30][30] f32 ;
// stats [2][256] f32 ; wp [36][16][4][16][8] bf16 = 589,824 (round-2 layout)
#define S_OFF   7372800
#define ST_OFF  7488000
#define WP_OFF  7490048
#define ZERO_F4 468128            // (ST_OFF + 2048) / 16 : zeroes xp + s + stats

#define SLAB_CHUNKS 4864          // 19*256; >= 10 rows * 30 * 16 = 4800

__device__ __forceinline__ unsigned short f2bf(float f) {
    unsigned int u = __float_as_uint(f);
    unsigned int r = (u + 0x7FFFu + ((u >> 16) & 1u)) >> 16;
    return (unsigned short)r;
}

__device__ __forceinline__ void gload_lds16(const void* gsrc, void* ldst) {
    __builtin_amdgcn_global_load_lds(
        (const __attribute__((address_space(1))) void*)gsrc,
        (__attribute__((address_space(3))) void*)ldst, 16, 0, 0);
}

__global__ __launch_bounds__(256) void init_ws(float* ws) {
    int i = blockIdx.x * 256 + threadIdx.x;
    if (i < ZERO_F4) ((f32x4*)ws)[i] = (f32x4){0.f, 0.f, 0.f, 0.f};
}

// ---- pack x: NCHW f32 -> padded NHWC bf16, plus s = sum_ci x^2 (round-2) ----
__global__ __launch_bounds__(256) void pack_x(const float* __restrict__ x,
                                              unsigned short* __restrict__ xp,
                                              float* __restrict__ s) {
    const int n = blockIdx.x / 28, h = blockIdx.x % 28, tid = threadIdx.x;
    __shared__ float xs[128][29];
    __shared__ float part[8][28];

    #pragma unroll
    for (int i = 0; i < 14; ++i) {
        int e = tid + i * 256;
        int ci = e / 28, w = e - ci * 28;
        xs[ci][w] = x[(size_t)(n * 128 + ci) * 784 + h * 28 + w];
    }
    __syncthreads();
    #pragma unroll
    for (int i = 0; i < 14; ++i) {
        int e = tid + i * 256;
        int w = e >> 7, ci = e & 127;
        xp[((size_t)(n * 30 + h + 1) * 30 + (w + 1)) * 128 + ci] = f2bf(xs[ci][w]);
    }
    if (tid < 224) {
        int grp = tid / 28, w = tid - grp * 28;
        float a = 0.f;
        #pragma unroll
        for (int ci = grp * 16; ci < grp * 16 + 16; ++ci) a = fmaf(xs[ci][w], xs[ci][w], a);
        part[grp][w] = a;
    }
    __syncthreads();
    if (tid < 28) {
        float a = 0.f;
        #pragma unroll
        for (int g = 0; g < 8; ++g) a += part[g][tid];
        s[n * 900 + (h + 1) * 30 + (tid + 1)] = a;
    }
}

// ---- pack w (round-2 verified): wp[kblk(36)][ng(16)][kb(4)][cc(16)][k8(8)] ----
__global__ __launch_bounds__(256) void pack_w(const float* __restrict__ w,
                                              unsigned short* __restrict__ wp) {
    int o = blockIdx.x * 256 + threadIdx.x;      // < 294912
    int k8   = o & 7;
    int cc   = (o >> 3) & 15;
    int kb   = (o >> 7) & 3;
    int ng   = (o >> 9) & 15;
    int kblk = o >> 13;                          // 0..35
    int tap  = kblk >> 2;
    int ci   = (kblk & 3) * 32 + kb * 8 + k8;
    int co   = ng * 16 + cc;
    wp[o] = f2bf(w[(size_t)(co * 128 + ci) * 9 + tap]);
}

// ---- MFMA implicit GEMM: BM=128, BN=64, 4 waves (2x2 of 64x32) ----
// A-slab resident in LDS (staged once, 10 rows); barrier-free K-loop;
// coalesced LDS-transpose epilogue (slab reused as float[64][132]).
__global__ __launch_bounds__(256, 2) void econv(
        const unsigned short* __restrict__ xp, const unsigned short* __restrict__ wp,
        const float* __restrict__ s, float* __restrict__ y, float* __restrict__ stats) {
    __shared__ unsigned short slab[SLAB_CHUNKS * 8];   // 77,824 B: 10 padded rows
    __shared__ float t1s[128];

    const int tid = threadIdx.x;
    // XCD-aware bijective swizzle (784 = 8*98)
    int bid = blockIdx.x;
    int swz = (bid & 7) * 98 + (bid >> 3);
    const int nb = swz & 3;
    const int mb = swz >> 2;
    const int gblock = mb * 128;
    const int nblock = nb * 64;
    const int ng0 = nb * 4;

    // slab covers global padded rows GR0..GR0+9 (crossing blocks need 10)
    const int n0  = gblock / 784;
    const int p0  = gblock - n0 * 784;
    const int GR0 = n0 * 30 + p0 / 28;
    const unsigned short* slabg = xp + (size_t)GR0 * 30 * 128;

    // stage slab once: linear LDS dest, source pre-swizzled.
    // slot sl of pixel Q holds source chunk c = (sl&8)|((sl&7)^(Q&7)).
    #pragma unroll
    for (int i = 0; i < 19; ++i) {
        int sc = tid + i * 256;
        int Q = sc >> 4, sl = sc & 15;
        int c = (sl & 8) | ((sl & 7) ^ (Q & 7));
        gload_lds16(slabg + (size_t)(Q * 16 + c) * 8, &slab[sc * 8]);
    }

    // t1 = 3x3 box of padded per-pixel sum of x^2
    if (tid < 128) {
        int g = gblock + tid; int n = g / 784, p = g - n * 784;
        int h = p / 28, wq = p - h * 28;
        const float* sb = s + n * 900 + h * 30 + wq;
        t1s[tid] = (sb[0] + sb[1] + sb[2]) + (sb[30] + sb[31] + sb[32]) + (sb[60] + sb[61] + sb[62]);
    }

    const int lane = tid & 63;
    const int wid  = tid >> 6;
    const int wm = wid >> 1, wn = wid & 1;
    const int l15 = lane & 15, l16 = lane >> 4;

    // per-lane slab pixel index (3x3 window top-left) for each fm row
    int Pp[4];
    #pragma unroll
    for (int fm = 0; fm < 4; ++fm) {
        int g = gblock + wm * 64 + fm * 16 + l15;
        int n = g / 784, p = g - n * 784;
        int h = p / 28, c = p - h * 28;
        Pp[fm] = (n * 30 + h - GR0) * 30 + c;
    }
    // per-lane B base: each wave's frag read is 1KB contiguous
    const unsigned short* wpl = wp + (size_t)((ng0 + wn * 2) * 64 + l16 * 16 + l15) * 8;

    f32x4 acc[4][2];
    #pragma unroll
    for (int a_ = 0; a_ < 4; ++a_)
        #pragma unroll
        for (int b_ = 0; b_ < 2; ++b_) acc[a_][b_] = (f32x4){0.f, 0.f, 0.f, 0.f};

    __syncthreads();   // slab + t1s ready; no barriers in K-loop

    #pragma unroll
    for (int tap = 0; tap < 9; ++tap) {
        const int toff = (tap / 3) * 30 + (tap % 3);
        #pragma unroll
        for (int half = 0; half < 2; ++half) {
            bf16x8 aF[2][4], bF[2][2];
            #pragma unroll
            for (int q = 0; q < 2; ++q) {
                #pragma unroll
                for (int fm = 0; fm < 4; ++fm) {
                    int P2 = Pp[fm] + toff;
                    int sl = half * 8 + ((q * 4 + l16) ^ (P2 & 7));
                    aF[q][fm] = *(const bf16x8*)&slab[(P2 * 16 + sl) * 8];
                }
                const int K16 = (tap * 4 + half * 2 + q) * 16;
                #pragma unroll
                for (int fn = 0; fn < 2; ++fn)
                    bF[q][fn] = *(const bf16x8*)&wpl[(size_t)(K16 + fn) * 512];
            }
            #pragma unroll
            for (int q = 0; q < 2; ++q)
                #pragma unroll
                for (int fm = 0; fm < 4; ++fm)
                    #pragma unroll
                    for (int fn = 0; fn < 2; ++fn)
                        acc[fm][fn] = __builtin_amdgcn_mfma_f32_16x16x32_bf16(
                            aF[q][fm], bF[q][fn], acc[fm][fn], 0, 0, 0);
        }
    }

    // ---- epilogue: coalesced via LDS transpose (slab reused) ----
    __syncthreads();   // all waves finished reading slab
    float* ldsT = (float*)slab;   // [64 co][132] floats = 33,792 B

    float sSum[2] = {0.f, 0.f}, sSq[2] = {0.f, 0.f};
    #pragma unroll
    for (int fm = 0; fm < 4; ++fm) {
        #pragma unroll
        for (int j = 0; j < 4; ++j) {
            int r = wm * 64 + fm * 16 + l16 * 4 + j;
            float t1v = t1s[r];
            #pragma unroll
            for (int fn = 0; fn < 2; ++fn) {
                float v = fmaf(2.f, acc[fm][fn][j], t1v);
                ldsT[(wn * 32 + fn * 16 + l15) * 132 + r] = v;
                float d = v - SHIFT_;
                sSum[fn] += d;
                sSq[fn] = fmaf(d, d, sSq[fn]);
            }
        }
    }
    __syncthreads();
    // coalesced store: thread reads f32x4 per (co, 4 consecutive pixels)
    #pragma unroll
    for (int i = 0; i < 8; ++i) {
        int idx = tid + i * 256;       // 0..2047
        int co  = idx >> 5;            // 0..63
        int r   = (idx & 31) * 4;      // block-local pixel, mult of 4
        int g   = gblock + r;
        int n = g / 784, p = g - n * 784;   // crossings at mult of 16: never split
        f32x4 v = *(const f32x4*)&ldsT[co * 132 + r];
        *(f32x4*)&y[(size_t)n * 200704 + (size_t)(nblock + co) * 784 + p] = v;
    }

    #pragma unroll
    for (int fn = 0; fn < 2; ++fn) {
        float a = sSum[fn], b2 = sSq[fn];
        a  += __shfl_xor(a, 16);  a  += __shfl_xor(a, 32);
        b2 += __shfl_xor(b2, 16); b2 += __shfl_xor(b2, 32);
        if (l16 == 0) {
            int co = nblock + wn * 32 + fn * 16 + l15;
            atomicAdd(&stats[co], a);
            atomicAdd(&stats[256 + co], b2);
        }
    }
}

__global__ __launch_bounds__(256) void bn_apply(
        float* __restrict__ y, const float* __restrict__ stats,
        const float* __restrict__ gamma, const float* __restrict__ beta) {
    const int TOTAL4 = NB_ * CO_ * NPIX / 4;
    int i4 = blockIdx.x * 256 + threadIdx.x;
    if (i4 >= TOTAL4) return;
    int c = (i4 / (NPIX / 4)) & (CO_ - 1);
    float su = stats[c];
    float s2 = stats[CO_ + c];
    const float invM = 1.0f / (float)M_TOT;
    float ms   = su * invM;
    float var  = fmaf(-ms, ms, s2 * invM);
    float mean = SHIFT_ + ms;
    float scale = rsqrtf(var + BN_EPS) * gamma[c];
    float bias  = beta[c] - mean * scale;
    f32x4 v = ((const f32x4*)y)[i4];
    v.x = fmaf(v.x, scale, bias);
    v.y = fmaf(v.y, scale, bias);
    v.z = fmaf(v.z, scale, bias);
    v.w = fmaf(v.w, scale, bias);
    ((f32x4*)y)[i4] = v;
}

extern "C" void kernel_launch(void* const* d_in, const int* in_sizes, int n_in,
                              void* d_out, int out_size, void* d_ws, size_t ws_size,
                              hipStream_t stream) {
    const float* x     = (const float*)d_in[0];
    const float* w     = (const float*)d_in[1];
    const float* gamma = (const float*)d_in[2];
    const float* beta  = (const float*)d_in[3];
    float* y = (float*)d_out;

    char* ws = (char*)d_ws;
    unsigned short* xp    = (unsigned short*)(ws);
    float*          s     = (float*)(ws + S_OFF);
    float*          stats = (float*)(ws + ST_OFF);
    unsigned short* wp    = (unsigned short*)(ws + WP_OFF);

    init_ws<<<(ZERO_F4 + 255) / 256, 256, 0, stream>>>((float*)ws);
    pack_x<<<NB_ * 28, 256, 0, stream>>>(x, xp, s);
    pack_w<<<1152, 256, 0, stream>>>(w, wp);
    econv<<<784, 256, 0, stream>>>(xp, wp, s, y, stats);
    bn_apply<<<(NB_ * CO_ * NPIX / 4 + 255) / 256, 256, 0, stream>>>(y, stats, gamma, beta);
}

// Round 9
// 55.627 us; speedup vs baseline: 1.4041x; 1.0237x over previous
//
#include <hip/hip_runtime.h>

// EuclidConv + BatchNorm (training stats), fp32 in/out.
// y = 2*conv(x,w) + t1 (+t2 cancels in BN).  bf16 MFMA implicit GEMM:
//   M=25088 pixels, N=256 chans, K=9 taps*128 ci.
// Round 9: round-8 verified base + ONE delta: explicit 1-step register
// software-pipeline of the K-loop (prefetch aF/bF for step k+1 before the
// MFMAs of step k). Compile-time [ks&1] indexing (loop fully unrolled).

typedef short  bf16x8 __attribute__((ext_vector_type(8)));
typedef float  f32x4  __attribute__((ext_vector_type(4)));

#define NPIX   784
#define CI_    128
#define CO_    256
#define NB_    32
#define M_     25088
#define SHIFT_ 1152.0f
#define BN_EPS 1e-5f
#define M_TOT  25088

// ws layout (bytes): xp [32][30][30][128] bf16 = 7,372,800 ; s [32][30][30] f32 ;
// stats [2][256] f32 ; wp [36][16][4][16][8] bf16 = 589,824 (round-2 layout)
#define S_OFF   7372800
#define ST_OFF  7488000
#define WP_OFF  7490048
#define ZERO_F4 468128            // (ST_OFF + 2048) / 16 : zeroes xp + s + stats

#define SLAB_CHUNKS 4864          // 19*256; >= 10 rows * 30 * 16 = 4800

__device__ __forceinline__ unsigned short f2bf(float f) {
    unsigned int u = __float_as_uint(f);
    unsigned int r = (u + 0x7FFFu + ((u >> 16) & 1u)) >> 16;
    return (unsigned short)r;
}

__device__ __forceinline__ void gload_lds16(const void* gsrc, void* ldst) {
    __builtin_amdgcn_global_load_lds(
        (const __attribute__((address_space(1))) void*)gsrc,
        (__attribute__((address_space(3))) void*)ldst, 16, 0, 0);
}

__global__ __launch_bounds__(256) void init_ws(float* ws) {
    int i = blockIdx.x * 256 + threadIdx.x;
    if (i < ZERO_F4) ((f32x4*)ws)[i] = (f32x4){0.f, 0.f, 0.f, 0.f};
}

// ---- pack x: NCHW f32 -> padded NHWC bf16, plus s = sum_ci x^2 (round-2) ----
__global__ __launch_bounds__(256) void pack_x(const float* __restrict__ x,
                                              unsigned short* __restrict__ xp,
                                              float* __restrict__ s) {
    const int n = blockIdx.x / 28, h = blockIdx.x % 28, tid = threadIdx.x;
    __shared__ float xs[128][29];
    __shared__ float part[8][28];

    #pragma unroll
    for (int i = 0; i < 14; ++i) {
        int e = tid + i * 256;
        int ci = e / 28, w = e - ci * 28;
        xs[ci][w] = x[(size_t)(n * 128 + ci) * 784 + h * 28 + w];
    }
    __syncthreads();
    #pragma unroll
    for (int i = 0; i < 14; ++i) {
        int e = tid + i * 256;
        int w = e >> 7, ci = e & 127;
        xp[((size_t)(n * 30 + h + 1) * 30 + (w + 1)) * 128 + ci] = f2bf(xs[ci][w]);
    }
    if (tid < 224) {
        int grp = tid / 28, w = tid - grp * 28;
        float a = 0.f;
        #pragma unroll
        for (int ci = grp * 16; ci < grp * 16 + 16; ++ci) a = fmaf(xs[ci][w], xs[ci][w], a);
        part[grp][w] = a;
    }
    __syncthreads();
    if (tid < 28) {
        float a = 0.f;
        #pragma unroll
        for (int g = 0; g < 8; ++g) a += part[g][tid];
        s[n * 900 + (h + 1) * 30 + (tid + 1)] = a;
    }
}

// ---- pack w (round-2 verified): wp[kblk(36)][ng(16)][kb(4)][cc(16)][k8(8)] ----
__global__ __launch_bounds__(256) void pack_w(const float* __restrict__ w,
                                              unsigned short* __restrict__ wp) {
    int o = blockIdx.x * 256 + threadIdx.x;      // < 294912
    int k8   = o & 7;
    int cc   = (o >> 3) & 15;
    int kb   = (o >> 7) & 3;
    int ng   = (o >> 9) & 15;
    int kblk = o >> 13;                          // 0..35
    int tap  = kblk >> 2;
    int ci   = (kblk & 3) * 32 + kb * 8 + k8;
    int co   = ng * 16 + cc;
    wp[o] = f2bf(w[(size_t)(co * 128 + ci) * 9 + tap]);
}

// ---- MFMA implicit GEMM: BM=128, BN=64, 4 waves (2x2 of 64x32) ----
// A-slab resident in LDS (staged once, 10 rows); barrier-free K-loop with
// 1-step register prefetch; coalesced LDS-transpose epilogue.
__global__ __launch_bounds__(256, 2) void econv(
        const unsigned short* __restrict__ xp, const unsigned short* __restrict__ wp,
        const float* __restrict__ s, float* __restrict__ y, float* __restrict__ stats) {
    __shared__ unsigned short slab[SLAB_CHUNKS * 8];   // 77,824 B: 10 padded rows
    __shared__ float t1s[128];

    const int tid = threadIdx.x;
    // XCD-aware bijective swizzle (784 = 8*98)
    int bid = blockIdx.x;
    int swz = (bid & 7) * 98 + (bid >> 3);
    const int nb = swz & 3;
    const int mb = swz >> 2;
    const int gblock = mb * 128;
    const int nblock = nb * 64;
    const int ng0 = nb * 4;

    // slab covers global padded rows GR0..GR0+9 (crossing blocks need 10)
    const int n0  = gblock / 784;
    const int p0  = gblock - n0 * 784;
    const int GR0 = n0 * 30 + p0 / 28;
    const unsigned short* slabg = xp + (size_t)GR0 * 30 * 128;

    // stage slab once: linear LDS dest, source pre-swizzled.
    // slot sl of pixel Q holds source chunk c = (sl&8)|((sl&7)^(Q&7)).
    #pragma unroll
    for (int i = 0; i < 19; ++i) {
        int sc = tid + i * 256;
        int Q = sc >> 4, sl = sc & 15;
        int c = (sl & 8) | ((sl & 7) ^ (Q & 7));
        gload_lds16(slabg + (size_t)(Q * 16 + c) * 8, &slab[sc * 8]);
    }

    // t1 = 3x3 box of padded per-pixel sum of x^2
    if (tid < 128) {
        int g = gblock + tid; int n = g / 784, p = g - n * 784;
        int h = p / 28, wq = p - h * 28;
        const float* sb = s + n * 900 + h * 30 + wq;
        t1s[tid] = (sb[0] + sb[1] + sb[2]) + (sb[30] + sb[31] + sb[32]) + (sb[60] + sb[61] + sb[62]);
    }

    const int lane = tid & 63;
    const int wid  = tid >> 6;
    const int wm = wid >> 1, wn = wid & 1;
    const int l15 = lane & 15, l16 = lane >> 4;

    // per-lane slab pixel index (3x3 window top-left) for each fm row
    int Pp[4];
    #pragma unroll
    for (int fm = 0; fm < 4; ++fm) {
        int g = gblock + wm * 64 + fm * 16 + l15;
        int n = g / 784, p = g - n * 784;
        int h = p / 28, c = p - h * 28;
        Pp[fm] = (n * 30 + h - GR0) * 30 + c;
    }
    // per-lane B base: each wave's frag read is 1KB contiguous
    const unsigned short* wpl = wp + (size_t)((ng0 + wn * 2) * 64 + l16 * 16 + l15) * 8;

    f32x4 acc[4][2];
    #pragma unroll
    for (int a_ = 0; a_ < 4; ++a_)
        #pragma unroll
        for (int b_ = 0; b_ < 2; ++b_) acc[a_][b_] = (f32x4){0.f, 0.f, 0.f, 0.f};

    __syncthreads();   // slab + t1s ready; no barriers in K-loop

#define LOADK(ks, A, B) {                                                    \
    const int tap_ = (ks) >> 1, half_ = (ks) & 1;                            \
    const int toff_ = (tap_ / 3) * 30 + (tap_ % 3);                          \
    _Pragma("unroll") for (int q_ = 0; q_ < 2; ++q_) {                       \
        _Pragma("unroll") for (int fm_ = 0; fm_ < 4; ++fm_) {                \
            int P2_ = Pp[fm_] + toff_;                                       \
            int sl_ = half_ * 8 + ((q_ * 4 + l16) ^ (P2_ & 7));              \
            A[q_][fm_] = *(const bf16x8*)&slab[(P2_ * 16 + sl_) * 8];        \
        }                                                                    \
        const int K16_ = (tap_ * 4 + half_ * 2 + q_) * 16;                   \
        _Pragma("unroll") for (int fn_ = 0; fn_ < 2; ++fn_)                  \
            B[q_][fn_] = *(const bf16x8*)&wpl[(size_t)(K16_ + fn_) * 512];   \
    }                                                                        \
}

    bf16x8 aP[2][2][4], bP[2][2][2];
    LOADK(0, aP[0], bP[0]);
    #pragma unroll
    for (int ks = 0; ks < 18; ++ks) {
        const int cur = ks & 1;          // compile-time after unroll
        if (ks < 17) LOADK(ks + 1, aP[cur ^ 1], bP[cur ^ 1]);
        #pragma unroll
        for (int q = 0; q < 2; ++q)
            #pragma unroll
            for (int fm = 0; fm < 4; ++fm)
                #pragma unroll
                for (int fn = 0; fn < 2; ++fn)
                    acc[fm][fn] = __builtin_amdgcn_mfma_f32_16x16x32_bf16(
                        aP[cur][q][fm], bP[cur][q][fn], acc[fm][fn], 0, 0, 0);
    }
#undef LOADK

    // ---- epilogue: coalesced via LDS transpose (slab reused) ----
    __syncthreads();   // all waves finished reading slab
    float* ldsT = (float*)slab;   // [64 co][132] floats = 33,792 B

    float sSum[2] = {0.f, 0.f}, sSq[2] = {0.f, 0.f};
    #pragma unroll
    for (int fm = 0; fm < 4; ++fm) {
        #pragma unroll
        for (int j = 0; j < 4; ++j) {
            int r = wm * 64 + fm * 16 + l16 * 4 + j;
            float t1v = t1s[r];
            #pragma unroll
            for (int fn = 0; fn < 2; ++fn) {
                float v = fmaf(2.f, acc[fm][fn][j], t1v);
                ldsT[(wn * 32 + fn * 16 + l15) * 132 + r] = v;
                float d = v - SHIFT_;
                sSum[fn] += d;
                sSq[fn] = fmaf(d, d, sSq[fn]);
            }
        }
    }
    __syncthreads();
    // coalesced store: thread reads f32x4 per (co, 4 consecutive pixels)
    #pragma unroll
    for (int i = 0; i < 8; ++i) {
        int idx = tid + i * 256;       // 0..2047
        int co  = idx >> 5;            // 0..63
        int r   = (idx & 31) * 4;      // block-local pixel, mult of 4
        int g   = gblock + r;
        int n = g / 784, p = g - n * 784;   // crossings at mult of 16: never split
        f32x4 v = *(const f32x4*)&ldsT[co * 132 + r];
        *(f32x4*)&y[(size_t)n * 200704 + (size_t)(nblock + co) * 784 + p] = v;
    }

    #pragma unroll
    for (int fn = 0; fn < 2; ++fn) {
        float a = sSum[fn], b2 = sSq[fn];
        a  += __shfl_xor(a, 16);  a  += __shfl_xor(a, 32);
        b2 += __shfl_xor(b2, 16); b2 += __shfl_xor(b2, 32);
        if (l16 == 0) {
            int co = nblock + wn * 32 + fn * 16 + l15;
            atomicAdd(&stats[co], a);
            atomicAdd(&stats[256 + co], b2);
        }
    }
}

__global__ __launch_bounds__(256) void bn_apply(
        float* __restrict__ y, const float* __restrict__ stats,
        const float* __restrict__ gamma, const float* __restrict__ beta) {
    const int TOTAL4 = NB_ * CO_ * NPIX / 4;
    int i4 = blockIdx.x * 256 + threadIdx.x;
    if (i4 >= TOTAL4) return;
    int c = (i4 / (NPIX / 4)) & (CO_ - 1);
    float su = stats[c];
    float s2 = stats[CO_ + c];
    const float invM = 1.0f / (float)M_TOT;
    float ms   = su * invM;
    float var  = fmaf(-ms, ms, s2 * invM);
    float mean = SHIFT_ + ms;
    float scale = rsqrtf(var + BN_EPS) * gamma[c];
    float bias  = beta[c] - mean * scale;
    f32x4 v = ((const f32x4*)y)[i4];
    v.x = fmaf(v.x, scale, bias);
    v.y = fmaf(v.y, scale, bias);
    v.z = fmaf(v.z, scale, bias);
    v.w = fmaf(v.w, scale, bias);
    ((f32x4*)y)[i4] = v;
}

extern "C" void kernel_launch(void* const* d_in, const int* in_sizes, int n_in,
                              void* d_out, int out_size, void* d_ws, size_t ws_size,
                              hipStream_t stream) {
    const float* x     = (const float*)d_in[0];
    const float* w     = (const float*)d_in[1];
    const float* gamma = (const float*)d_in[2];
    const float* beta  = (const float*)d_in[3];
    float* y = (float*)d_out;

    char* ws = (char*)d_ws;
    unsigned short* xp    = (unsigned short*)(ws);
    float*          s     = (float*)(ws + S_OFF);
    float*          stats = (float*)(ws + ST_OFF);
    unsigned short* wp    = (unsigned short*)(ws + WP_OFF);

    init_ws<<<(ZERO_F4 + 255) / 256, 256, 0, stream>>>((float*)ws);
    pack_x<<<NB_ * 28, 256, 0, stream>>>(x, xp, s);
    pack_w<<<1152, 256, 0, stream>>>(w, wp);
    econv<<<784, 256, 0, stream>>>(xp, wp, s, y, stats);
    bn_apply<<<(NB_ * CO_ * NPIX / 4 + 255) / 256, 256, 0, stream>>>(y, stats, gamma, beta);
}